// Round 8
// baseline (175.789 us; speedup 1.0000x reference)
//
#include <hip/hip_runtime.h>
#include <hip/hip_bf16.h>
#include <cstddef>

// Problem constants (B=8, S1=256, S2=64, VIDEO=1024, TEXT=768, ATTN=512, OUT=500)
#define MBP   2048   // B*S1
#define MT    512    // B*S2
#define ADIM  512
#define VDIM  1024
#define TDIM  768
#define NOUT  500
#define CDIM  2048   // 4*ADIM

typedef __attribute__((ext_vector_type(8))) short short8;    // 8 bf16 = 4 VGPRs
typedef __attribute__((ext_vector_type(4))) float floatx4;   // MFMA C/D frag

// tanh via native exp2 + rcp: rel err ~1e-6.
__device__ __forceinline__ float tanh_fast(float x) {
    float e = __builtin_amdgcn_exp2f(x * 2.88539008177793f);
    float r = __builtin_amdgcn_rcpf(e + 1.0f);
    return __builtin_fmaf(-2.0f, r, 1.0f);
}

__device__ __forceinline__ unsigned short bf16r(float x) {
    union { float f; unsigned int u; } c; c.f = x;
    unsigned int r = (c.u + 0x7fffu + ((c.u >> 16) & 1u)) >> 16;
    return (unsigned short)r;
}
__device__ __forceinline__ float bf2f(unsigned short h) {
    union { unsigned int u; float f; } c; c.u = ((unsigned int)h) << 16;
    return c.f;
}

// ROUND-TO-NEAREST hi/lo split of 8 fp32 -> packed bf16x8 hi + lo.
// h = rne16(f); l = rne16(f - h). Residual ~2^-18 relative, unbiased.
// (Round 7's trunc-based split regressed absmax 2.06 -> 4.625: 4x residual
//  + toward-zero bias on logits/scores. Keep rounding.)
__device__ __forceinline__ void split8(float4 a, float4 b, uint4& h, uint4& l) {
    float f[8] = {a.x, a.y, a.z, a.w, b.x, b.y, b.z, b.w};
    unsigned int hu[8], lu[8];
    #pragma unroll
    for (int i = 0; i < 8; ++i) {
        unsigned short hh = bf16r(f[i]);
        hu[i] = hh;
        lu[i] = bf16r(f[i] - bf2f(hh));
    }
    h.x = hu[0] | (hu[1] << 16);
    h.y = hu[2] | (hu[3] << 16);
    h.z = hu[4] | (hu[5] << 16);
    h.w = hu[6] | (hu[7] << 16);
    l.x = lu[0] | (lu[1] << 16);
    l.y = lu[2] | (lu[3] << 16);
    l.z = lu[4] | (lu[5] << 16);
    l.w = lu[6] | (lu[7] << 16);
}

__device__ __forceinline__ void split8s(const float* p, short8& hh, short8& ll) {
    float4 a = *(const float4*)p, b = *(const float4*)(p + 4);
    uint4 h, l; split8(a, b, h, l);
    hh = *(short8*)&h; ll = *(short8*)&l;
}

// ---------------- prep: weight transposes only (one dispatch) ---------------
__device__ __forceinline__ void transp_split_body(
    float (*tile)[33], const float* __restrict__ src,
    unsigned short* __restrict__ hi, unsigned short* __restrict__ lo,
    int R, int C, int bx, int by)
{
    const int tx = threadIdx.x & 31, ty = threadIdx.x >> 5;
    const int r0 = bx * 32, c0 = by * 32;
    #pragma unroll
    for (int i = 0; i < 4; ++i) {
        int r = r0 + ty + i * 8, c = c0 + tx;
        if (r < R && c < C) tile[ty + i * 8][tx] = src[(size_t)r * C + c];
    }
    __syncthreads();
    #pragma unroll
    for (int i = 0; i < 4; ++i) {
        int c = c0 + ty + i * 8, r = r0 + tx;
        if (c < C && r < R) {
            float v = tile[tx][ty + i * 8];
            unsigned short h = bf16r(v);
            hi[(size_t)c * R + r] = h;
            lo[(size_t)c * R + r] = bf16r(v - bf2f(h));
        }
    }
}

__device__ __forceinline__ void transp_single_body(
    float (*tile)[33], const float* __restrict__ src,
    unsigned short* __restrict__ dst, int R, int C, int bx, int by)
{
    const int tx = threadIdx.x & 31, ty = threadIdx.x >> 5;
    const int r0 = bx * 32, c0 = by * 32;
    #pragma unroll
    for (int i = 0; i < 4; ++i) {
        int r = r0 + ty + i * 8, c = c0 + tx;
        if (r < R && c < C) tile[ty + i * 8][tx] = src[(size_t)r * C + c];
    }
    __syncthreads();
    #pragma unroll
    for (int i = 0; i < 4; ++i) {
        int c = c0 + ty + i * 8, r = r0 + tx;
        if (c < C && r < R) dst[(size_t)c * R + r] = bf16r(tile[tx][ty + i * 8]);
    }
}

// blocks: [0,512) w1 (32x16 tiles); [512,896) w2 (24x16); [896,1920) w4 (64x16)
__global__ __launch_bounds__(256) void prep(
    const float* __restrict__ w1, const float* __restrict__ w2,
    const float* __restrict__ w4,
    unsigned short* __restrict__ w1t_h, unsigned short* __restrict__ w1t_l,
    unsigned short* __restrict__ w2t_h, unsigned short* __restrict__ w2t_l,
    unsigned short* __restrict__ w4t)
{
    __shared__ float tile[32][33];
    const int bid = blockIdx.x;
    if (bid < 512) {
        transp_split_body(tile, w1, w1t_h, w1t_l, VDIM, ADIM, bid & 31, bid >> 5);
    } else if (bid < 896) {
        int idx = bid - 512;
        transp_split_body(tile, w2, w2t_h, w2t_l, TDIM, ADIM, idx % 24, idx / 24);
    } else {
        int idx = bid - 896;
        transp_single_body(tile, w4, w4t, CDIM, NOUT, idx >> 4, idx & 15);
    }
}

#define LP 40   // LDS row pitch in ushorts (80 B: 16-B aligned, odd bank stride)

// Compensated bf16 MFMA GEMM, dbuf-pipelined, A split INLINE from fp32.
// bx in [0,64): h1 K-split halves (part = bx>>5), output h1p[part][2048][512].
// bx in [64,72): h2 full K=768; epilogue writes h2 fp32 + transposed split h2t.
__global__ __launch_bounds__(256) void gemm3_both(
    const float* __restrict__ video, const float* __restrict__ text,
    const unsigned short* __restrict__ w1t_h, const unsigned short* __restrict__ w1t_l,
    const unsigned short* __restrict__ w2t_h, const unsigned short* __restrict__ w2t_l,
    float* __restrict__ h1p, float* __restrict__ h2,
    unsigned short* __restrict__ h2t_h, unsigned short* __restrict__ h2t_l)
{
    __shared__ __align__(16) unsigned short Ahs[2][64 * LP];
    __shared__ __align__(16) unsigned short Als[2][64 * LP];
    __shared__ __align__(16) unsigned short Bhs[2][64 * LP];
    __shared__ __align__(16) unsigned short Bls[2][64 * LP];

    const int bx = blockIdx.x;
    const bool isH2 = (bx >= 64);
    const float* Afp; const unsigned short *Bh, *Bl;
    float* C;
    int Kfull, kbase, nIter, row0;
    if (!isH2) {
        Afp = video; Bh = w1t_h; Bl = w1t_l;
        Kfull = VDIM; kbase = (bx >> 5) * 512; nIter = 16;
        row0 = (bx & 31) * 64;
        C = h1p + (size_t)(bx >> 5) * MBP * ADIM;
    } else {
        Afp = text; Bh = w2t_h; Bl = w2t_l;
        Kfull = TDIM; kbase = 0; nIter = 24;
        row0 = (bx - 64) * 64;
        C = h2;
    }

    const int t = threadIdx.x;
    const int r  = t >> 2;
    const int kc = (t & 3) << 3;
    const int col0 = blockIdx.y * 64;
    const int wave = t >> 6, lane = t & 63;
    const int m15 = lane & 15, q8 = (lane >> 4) << 3;

    const size_t aoff = (size_t)(row0 + r) * Kfull + kbase + kc;
    const size_t boff = (size_t)(col0 + r) * Kfull + kbase + kc;

    floatx4 acc[4] = { {0.f,0.f,0.f,0.f}, {0.f,0.f,0.f,0.f},
                       {0.f,0.f,0.f,0.f}, {0.f,0.f,0.f,0.f} };

    float4 a0 = *(const float4*)(Afp + aoff);
    float4 a1 = *(const float4*)(Afp + aoff + 4);
    uint4 bvh = *(const uint4*)(Bh + boff);
    uint4 bvl = *(const uint4*)(Bl + boff);
    {
        uint4 avh, avl; split8(a0, a1, avh, avl);
        *(uint4*)&Ahs[0][r * LP + kc] = avh;
        *(uint4*)&Als[0][r * LP + kc] = avl;
        *(uint4*)&Bhs[0][r * LP + kc] = bvh;
        *(uint4*)&Bls[0][r * LP + kc] = bvl;
    }

    for (int i = 0; i < nIter; ++i) {
        __syncthreads();
        if (i + 1 < nIter) {
            int k0 = (i + 1) << 5;
            a0 = *(const float4*)(Afp + aoff + k0);
            a1 = *(const float4*)(Afp + aoff + k0 + 4);
            bvh = *(const uint4*)(Bh + boff + k0);
            bvl = *(const uint4*)(Bl + boff + k0);
        }
        const int cur = i & 1;
        short8 afh = *(const short8*)&Ahs[cur][(wave * 16 + m15) * LP + q8];
        short8 afl = *(const short8*)&Als[cur][(wave * 16 + m15) * LP + q8];
        #pragma unroll
        for (int j = 0; j < 4; ++j) {
            short8 bfh = *(const short8*)&Bhs[cur][(j * 16 + m15) * LP + q8];
            short8 bfl = *(const short8*)&Bls[cur][(j * 16 + m15) * LP + q8];
            acc[j] = __builtin_amdgcn_mfma_f32_16x16x32_bf16(afh, bfh, acc[j], 0, 0, 0);
            acc[j] = __builtin_amdgcn_mfma_f32_16x16x32_bf16(afh, bfl, acc[j], 0, 0, 0);
            acc[j] = __builtin_amdgcn_mfma_f32_16x16x32_bf16(afl, bfh, acc[j], 0, 0, 0);
        }
        if (i + 1 < nIter) {
            const int nxt = cur ^ 1;
            uint4 avh, avl; split8(a0, a1, avh, avl);
            *(uint4*)&Ahs[nxt][r * LP + kc] = avh;
            *(uint4*)&Als[nxt][r * LP + kc] = avl;
            *(uint4*)&Bhs[nxt][r * LP + kc] = bvh;
            *(uint4*)&Bls[nxt][r * LP + kc] = bvl;
        }
    }

    // C/D layout: col = lane&15, row = (lane>>4)*4 + reg
    const int rbase = row0 + wave * 16 + (q8 >> 1);
    #pragma unroll
    for (int j = 0; j < 4; ++j) {
        int col = col0 + j * 16 + m15;
        #pragma unroll
        for (int rr = 0; rr < 4; ++rr) {
            int row = rbase + rr;
            float v = acc[j][rr];
            C[(size_t)row * ADIM + col] = v;
            if (isH2) {
                // h2t[b][a][q]: b=row>>6, q=row&63, a=col
                size_t idx = (size_t)(row >> 6) * (ADIM * 64) + (size_t)col * 64 + (row & 63);
                unsigned short h = bf16r(v);
                h2t_h[idx] = h;
                h2t_l[idx] = bf16r(v - bf2f(h));
            }
        }
    }
}

// Additive-attention logits + softmax, lane<->a layout.
__global__ __launch_bounds__(256, 4) void attn_scores(
    const float* __restrict__ h1p,   // [2][2048][512] K-split partials
    const float* __restrict__ h2,    // [8][64][512]
    const float* __restrict__ bias,  // [512]
    const float* __restrict__ w3,    // [512]
    float* __restrict__ sc)          // [2048][64] fp32 softmaxed
{
    __shared__ float h2s[64][132];   // 33.8 KB; also reused as reduce scratch

    const int bp0 = blockIdx.x * 4;
    const int b   = bp0 >> 8;
    const int t   = threadIdx.x, wave = t >> 6, lane = t & 63;
    const int p   = bp0 + wave;
    const float* h2b  = h2 + (size_t)b * 64 * ADIM;
    const float* h1a  = h1p + (size_t)p * ADIM;
    const float* h1b2 = h1p + (size_t)MBP * ADIM + (size_t)p * ADIM;

    float acc[64];
    #pragma unroll
    for (int q = 0; q < 64; ++q) acc[q] = 0.f;

    const int qrow = t >> 2, cch = t & 3;
    #pragma unroll 1
    for (int tile = 0; tile < 4; ++tile) {
        const int a0 = tile * 128;
        __syncthreads();   // prior tile's readers done
        #pragma unroll
        for (int j = 0; j < 8; ++j) {
            float4 v = *(const float4*)(h2b + (size_t)qrow * ADIM + a0 + (cch + 4 * j) * 4);
            *(float4*)&h2s[qrow][(cch + 4 * j) * 4] = v;
        }
        __syncthreads();
        const int ag0 = a0 + lane, ag1 = ag0 + 64;
        const float c0  = h1a[ag0] + h1b2[ag0] + bias[ag0];
        const float c1  = h1a[ag1] + h1b2[ag1] + bias[ag1];
        const float w30 = w3[ag0], w31 = w3[ag1];
        const float* hp = &h2s[0][lane];
        #pragma unroll
        for (int q = 0; q < 64; ++q) {
            acc[q] = __builtin_fmaf(tanh_fast(c0 + hp[q * 132]),      w30, acc[q]);
            acc[q] = __builtin_fmaf(tanh_fast(c1 + hp[q * 132 + 64]), w31, acc[q]);
        }
    }
    __syncthreads();       // all waves done with h2s before scratch reuse

    float* scr = &h2s[0][0] + wave * 2112;   // 64x33 fp32 per wave
    float e = 0.f;
    #pragma unroll 1
    for (int hf = 0; hf < 2; ++hf) {
        #pragma unroll
        for (int q = 0; q < 32; ++q) scr[lane * 33 + q] = acc[hf * 32 + q];
        float part = 0.f;
        const int qq = lane & 31, r0 = (lane >> 5) * 32;
        #pragma unroll
        for (int j = 0; j < 32; ++j) part += scr[(r0 + j) * 33 + qq];
        part += __shfl_xor(part, 32, 64);
        if ((lane >> 5) == hf) e = part;
    }

    // softmax across the wave (lane = q)
    float m = e;
    #pragma unroll
    for (int off = 32; off; off >>= 1) m = fmaxf(m, __shfl_xor(m, off, 64));
    float ex = __builtin_amdgcn_exp2f((e - m) * 1.44269504088896f);
    float s = ex;
    #pragma unroll
    for (int off = 32; off; off >>= 1) s += __shfl_xor(s, off, 64);
    sc[(size_t)p * 64 + lane] = ex * __builtin_amdgcn_rcpf(s);
}

// text_attn = scores @ h2 via compensated MFMA (scores rne-split in-register
// from fp32) + cont-feature epilogue -> tc bf16.
__global__ __launch_bounds__(256) void ta_cont(
    const float* __restrict__ sc32,            // [2048][64] fp32
    const unsigned short* __restrict__ h2t_h,  // [8][512][64]
    const unsigned short* __restrict__ h2t_l,  // [8][512][64]
    const float* __restrict__ h1p,             // [2][2048][512]
    unsigned short* __restrict__ tcont)        // [2048][2048] bf16
{
    const int row0 = blockIdx.x * 64;
    const int col0 = blockIdx.y * 64;
    const int b = row0 >> 8;
    const int t = threadIdx.x;
    const int wave = t >> 6, lane = t & 63;
    const int m15 = lane & 15, q8 = (lane >> 4) << 3;

    const float* ap = sc32 + (size_t)(row0 + wave * 16 + m15) * 64;
    short8 af0h, af0l, af1h, af1l;
    split8s(ap + q8, af0h, af0l);
    split8s(ap + q8 + 32, af1h, af1l);
    const size_t bbase = (size_t)b * ADIM * 64;

    floatx4 acc[4];
    #pragma unroll
    for (int j = 0; j < 4; ++j) {
        size_t boff = bbase + (size_t)(col0 + j * 16 + m15) * 64 + q8;
        short8 bf0h = *(const short8*)&h2t_h[boff];
        short8 bf1h = *(const short8*)&h2t_h[boff + 32];
        short8 bf0l = *(const short8*)&h2t_l[boff];
        short8 bf1l = *(const short8*)&h2t_l[boff + 32];
        floatx4 z = {0.f, 0.f, 0.f, 0.f};
        z = __builtin_amdgcn_mfma_f32_16x16x32_bf16(af0h, bf0h, z, 0, 0, 0);
        z = __builtin_amdgcn_mfma_f32_16x16x32_bf16(af0h, bf0l, z, 0, 0, 0);
        z = __builtin_amdgcn_mfma_f32_16x16x32_bf16(af0l, bf0h, z, 0, 0, 0);
        z = __builtin_amdgcn_mfma_f32_16x16x32_bf16(af1h, bf1h, z, 0, 0, 0);
        z = __builtin_amdgcn_mfma_f32_16x16x32_bf16(af1h, bf1l, z, 0, 0, 0);
        acc[j] = __builtin_amdgcn_mfma_f32_16x16x32_bf16(af1l, bf1h, z, 0, 0, 0);
    }

    const float* h1a  = h1p;
    const float* h1b2 = h1p + (size_t)MBP * ADIM;
    const int rbase = row0 + wave * 16 + (q8 >> 1);
    #pragma unroll
    for (int j = 0; j < 4; ++j) {
        int a = col0 + j * 16 + m15;
        #pragma unroll
        for (int rr = 0; rr < 4; ++rr) {
            int row = rbase + rr;
            float ta = acc[j][rr];
            size_t hi = (size_t)row * ADIM + a;
            float hh = h1a[hi] + h1b2[hi];
            unsigned short* o = tcont + (size_t)row * CDIM;
            o[a]            = bf16r(tanh_fast(hh));
            o[ADIM + a]     = bf16r(tanh_fast(ta));
            o[2 * ADIM + a] = bf16r(tanh_fast(hh * ta));
            o[3 * ADIM + a] = bf16r(tanh_fast(hh - ta));
        }
    }
}

// Final GEMM, K-split x4 via blockIdx.z -> fp32 partials (pitch 512, no bias).
__global__ __launch_bounds__(256) void gemm_bf16(
    const unsigned short* __restrict__ A, const unsigned short* __restrict__ Bt,
    float* __restrict__ P)
{
    __shared__ __align__(16) unsigned short As[2][64 * LP];
    __shared__ __align__(16) unsigned short Bs[2][64 * LP];

    const int t = threadIdx.x;
    const int r  = t >> 2;
    const int kc = (t & 3) << 3;
    const int row0 = blockIdx.x * 64, col0 = blockIdx.y * 64;
    const int kbase = blockIdx.z * 512;
    const int wave = t >> 6, lane = t & 63;
    const int m15 = lane & 15, q8 = (lane >> 4) << 3;

    const unsigned short* Ap = A + (size_t)(row0 + r) * CDIM + kbase + kc;
    const int bn = col0 + r;
    const unsigned short* Bp = Bt + (size_t)bn * CDIM + kbase + kc;
    const bool bvalid = (bn < NOUT);

    floatx4 acc[4] = { {0.f,0.f,0.f,0.f}, {0.f,0.f,0.f,0.f},
                       {0.f,0.f,0.f,0.f}, {0.f,0.f,0.f,0.f} };

    uint4 av = *(const uint4*)Ap;
    uint4 bv = {0u,0u,0u,0u};
    if (bvalid) bv = *(const uint4*)Bp;
    *(uint4*)&As[0][r * LP + kc] = av;
    *(uint4*)&Bs[0][r * LP + kc] = bv;

    const int nIter = 16;
    for (int i = 0; i < nIter; ++i) {
        __syncthreads();
        if (i + 1 < nIter) {
            int k0 = (i + 1) << 5;
            av = *(const uint4*)(Ap + k0);
            if (bvalid) bv = *(const uint4*)(Bp + k0);
        }
        const int cur = i & 1;
        short8 af = *(const short8*)&As[cur][(wave * 16 + m15) * LP + q8];
        #pragma unroll
        for (int j = 0; j < 4; ++j) {
            short8 bf = *(const short8*)&Bs[cur][(j * 16 + m15) * LP + q8];
            acc[j] = __builtin_amdgcn_mfma_f32_16x16x32_bf16(af, bf, acc[j], 0, 0, 0);
        }
        if (i + 1 < nIter) {
            const int nxt = cur ^ 1;
            *(uint4*)&As[nxt][r * LP + kc] = av;
            *(uint4*)&Bs[nxt][r * LP + kc] = bv;
        }
    }

    float* Pz = P + (size_t)blockIdx.z * MBP * 512;
    const int rbase = row0 + wave * 16 + (q8 >> 1);
    #pragma unroll
    for (int j = 0; j < 4; ++j) {
        int col = col0 + j * 16 + m15;
        if (col < NOUT) {
            #pragma unroll
            for (int rr = 0; rr < 4; ++rr)
                Pz[(size_t)(rbase + rr) * 512 + col] = acc[j][rr];
        }
    }
}

// out[row][col] = b4[col] + sum_z part[z][row][col]; float2 per thread.
__global__ __launch_bounds__(256) void reduce_bias(
    const float* __restrict__ P, const float* __restrict__ b4,
    float* __restrict__ out)
{
    int i = blockIdx.x * 256 + threadIdx.x;      // float2 index
    if (i >= MBP * (NOUT / 2)) return;
    int row = i / (NOUT / 2);
    int col = (i - row * (NOUT / 2)) * 2;
    const float* p = P + (size_t)row * 512 + col;
    float2 v = *(const float2*)(b4 + col);
    #pragma unroll
    for (int z = 0; z < 4; ++z) {
        float2 q = *(const float2*)(p + (size_t)z * MBP * 512);
        v.x += q.x; v.y += q.y;
    }
    *(float2*)(out + (size_t)row * NOUT + col) = v;
}

extern "C" void kernel_launch(void* const* d_in, const int* in_sizes, int n_in,
                              void* d_out, int out_size, void* d_ws, size_t ws_size,
                              hipStream_t stream) {
    const float* video = (const float*)d_in[0];  // [8,256,1024]
    const float* text  = (const float*)d_in[1];  // [8,64,768]
    // masks (d_in[2], d_in[3]) are dead in the reference
    const float* w1   = (const float*)d_in[4];   // [1024,512]
    const float* w2   = (const float*)d_in[5];   // [768,512]
    const float* w3   = (const float*)d_in[6];   // [512,1]
    const float* bias = (const float*)d_in[7];   // [512]
    const float* w4   = (const float*)d_in[8];   // [2048,500]
    const float* b4   = (const float*)d_in[9];   // [500]
    float* out = (float*)d_out;                  // [8,256,500]

    char* ws = (char*)d_ws;
    size_t off = 0;
    unsigned short* w1t_h = (unsigned short*)(ws + off); off += (size_t)ADIM * VDIM * 2;
    unsigned short* w1t_l = (unsigned short*)(ws + off); off += (size_t)ADIM * VDIM * 2;
    unsigned short* w2t_h = (unsigned short*)(ws + off); off += (size_t)ADIM * TDIM * 2;
    unsigned short* w2t_l = (unsigned short*)(ws + off); off += (size_t)ADIM * TDIM * 2;
    unsigned short* w4t   = (unsigned short*)(ws + off); off += (size_t)NOUT * CDIM * 2;
    float*          h1p   = (float*)(ws + off);          off += (size_t)2 * MBP * ADIM * 4;
    float*          h2    = (float*)(ws + off);          off += (size_t)MT * ADIM * 4;
    unsigned short* h2t_h = (unsigned short*)(ws + off); off += (size_t)8 * ADIM * 64 * 2;
    unsigned short* h2t_l = (unsigned short*)(ws + off); off += (size_t)8 * ADIM * 64 * 2;
    float*          sc32  = (float*)(ws + off);          off += (size_t)MBP * 64 * 4;
    unsigned short* tc    = (unsigned short*)(ws + off); off += (size_t)MBP * CDIM * 2;
    float*          gpart = (float*)(ws + off);          off += (size_t)4 * MBP * 512 * 4;

    // 1) weight transposes (w1/w2 split, w4 single)
    prep<<<1920, 256, 0, stream>>>(w1, w2, w4, w1t_h, w1t_l, w2t_h, w2t_l, w4t);

    // 2) h1 (K-split x2 partials) & h2 GEMMs, A converted inline; h2t epilogue
    gemm3_both<<<dim3(72, 8), 256, 0, stream>>>(video, text, w1t_h, w1t_l,
                                                w2t_h, w2t_l, h1p, h2, h2t_h, h2t_l);

    // 3) logits + softmax -> fp32 scores
    attn_scores<<<MBP / 4, 256, 0, stream>>>(h1p, h2, bias, w3, sc32);

    // 4) text_attn MFMA + cont features -> tc bf16
    ta_cont<<<dim3(MBP / 64, ADIM / 64), 256, 0, stream>>>(sc32, h2t_h, h2t_l, h1p, tc);

    // 5) out partials: tanh(cont) @ w4, K-split x4
    gemm_bf16<<<dim3(MBP / 64, 8, 4), 256, 0, stream>>>(tc, w4t, gpart);

    // 6) sum partials + bias
    reduce_bias<<<(MBP * (NOUT / 2) + 255) / 256, 256, 0, stream>>>(gpart, b4, out);
}

// Round 9
// 160.250 us; speedup vs baseline: 1.0970x; 1.0970x over previous
//
#include <hip/hip_runtime.h>
#include <hip/hip_bf16.h>
#include <cstddef>

// Problem constants (B=8, S1=256, S2=64, VIDEO=1024, TEXT=768, ATTN=512, OUT=500)
#define MBP   2048   // B*S1
#define MT    512    // B*S2
#define ADIM  512
#define VDIM  1024
#define TDIM  768
#define NOUT  500
#define CDIM  2048   // 4*ADIM

typedef __attribute__((ext_vector_type(8))) short short8;    // 8 bf16 = 4 VGPRs
typedef __attribute__((ext_vector_type(4))) float floatx4;   // MFMA C/D frag

// tanh via native exp2 + rcp: rel err ~1e-6.
__device__ __forceinline__ float tanh_fast(float x) {
    float e = __builtin_amdgcn_exp2f(x * 2.88539008177793f);
    float r = __builtin_amdgcn_rcpf(e + 1.0f);
    return __builtin_fmaf(-2.0f, r, 1.0f);
}

__device__ __forceinline__ unsigned short bf16r(float x) {
    union { float f; unsigned int u; } c; c.f = x;
    unsigned int r = (c.u + 0x7fffu + ((c.u >> 16) & 1u)) >> 16;
    return (unsigned short)r;
}
__device__ __forceinline__ float bf2f(unsigned short h) {
    union { unsigned int u; float f; } c; c.u = ((unsigned int)h) << 16;
    return c.f;
}

// ROUND-TO-NEAREST hi/lo split of 8 fp32 -> packed bf16x8 hi + lo.
// (Trunc-based split regressed absmax 2.06 -> 4.625 in round 7. Keep RNE.)
__device__ __forceinline__ void split8(float4 a, float4 b, uint4& h, uint4& l) {
    float f[8] = {a.x, a.y, a.z, a.w, b.x, b.y, b.z, b.w};
    unsigned int hu[8], lu[8];
    #pragma unroll
    for (int i = 0; i < 8; ++i) {
        unsigned short hh = bf16r(f[i]);
        hu[i] = hh;
        lu[i] = bf16r(f[i] - bf2f(hh));
    }
    h.x = hu[0] | (hu[1] << 16);
    h.y = hu[2] | (hu[3] << 16);
    h.z = hu[4] | (hu[5] << 16);
    h.w = hu[6] | (hu[7] << 16);
    l.x = lu[0] | (lu[1] << 16);
    l.y = lu[2] | (lu[3] << 16);
    l.z = lu[4] | (lu[5] << 16);
    l.w = lu[6] | (lu[7] << 16);
}

__device__ __forceinline__ void split8s(const float* p, short8& hh, short8& ll) {
    float4 a = *(const float4*)p, b = *(const float4*)(p + 4);
    uint4 h, l; split8(a, b, h, l);
    hh = *(short8*)&h; ll = *(short8*)&l;
}

// ---------------- prep: weight transposes only (one dispatch) ---------------
__device__ __forceinline__ void transp_split_body(
    float (*tile)[33], const float* __restrict__ src,
    unsigned short* __restrict__ hi, unsigned short* __restrict__ lo,
    int R, int C, int bx, int by)
{
    const int tx = threadIdx.x & 31, ty = threadIdx.x >> 5;
    const int r0 = bx * 32, c0 = by * 32;
    #pragma unroll
    for (int i = 0; i < 4; ++i) {
        int r = r0 + ty + i * 8, c = c0 + tx;
        if (r < R && c < C) tile[ty + i * 8][tx] = src[(size_t)r * C + c];
    }
    __syncthreads();
    #pragma unroll
    for (int i = 0; i < 4; ++i) {
        int c = c0 + ty + i * 8, r = r0 + tx;
        if (c < C && r < R) {
            float v = tile[tx][ty + i * 8];
            unsigned short h = bf16r(v);
            hi[(size_t)c * R + r] = h;
            lo[(size_t)c * R + r] = bf16r(v - bf2f(h));
        }
    }
}

__device__ __forceinline__ void transp_single_body(
    float (*tile)[33], const float* __restrict__ src,
    unsigned short* __restrict__ dst, int R, int C, int bx, int by)
{
    const int tx = threadIdx.x & 31, ty = threadIdx.x >> 5;
    const int r0 = bx * 32, c0 = by * 32;
    #pragma unroll
    for (int i = 0; i < 4; ++i) {
        int r = r0 + ty + i * 8, c = c0 + tx;
        if (r < R && c < C) tile[ty + i * 8][tx] = src[(size_t)r * C + c];
    }
    __syncthreads();
    #pragma unroll
    for (int i = 0; i < 4; ++i) {
        int c = c0 + ty + i * 8, r = r0 + tx;
        if (c < C && r < R) dst[(size_t)c * R + r] = bf16r(tile[tx][ty + i * 8]);
    }
}

// blocks: [0,512) w1 (32x16 tiles); [512,896) w2 (24x16); [896,1920) w4 (64x16)
__global__ __launch_bounds__(256) void prep(
    const float* __restrict__ w1, const float* __restrict__ w2,
    const float* __restrict__ w4,
    unsigned short* __restrict__ w1t_h, unsigned short* __restrict__ w1t_l,
    unsigned short* __restrict__ w2t_h, unsigned short* __restrict__ w2t_l,
    unsigned short* __restrict__ w4t)
{
    __shared__ float tile[32][33];
    const int bid = blockIdx.x;
    if (bid < 512) {
        transp_split_body(tile, w1, w1t_h, w1t_l, VDIM, ADIM, bid & 31, bid >> 5);
    } else if (bid < 896) {
        int idx = bid - 512;
        transp_split_body(tile, w2, w2t_h, w2t_l, TDIM, ADIM, idx % 24, idx / 24);
    } else {
        int idx = bid - 896;
        transp_single_body(tile, w4, w4t, CDIM, NOUT, idx >> 4, idx & 15);
    }
}

#define LP 40   // LDS row pitch in ushorts (80 B: 16-B aligned, odd bank stride)

// Compensated bf16 MFMA GEMM, dbuf-pipelined, A split INLINE from fp32.
// bx in [0,64): h1 K-split halves (part = bx>>5), output h1p[part][2048][512].
// bx in [64,72): h2 full K=768; epilogue writes h2 fp32 + transposed split h2t.
__global__ __launch_bounds__(256) void gemm3_both(
    const float* __restrict__ video, const float* __restrict__ text,
    const unsigned short* __restrict__ w1t_h, const unsigned short* __restrict__ w1t_l,
    const unsigned short* __restrict__ w2t_h, const unsigned short* __restrict__ w2t_l,
    float* __restrict__ h1p, float* __restrict__ h2,
    unsigned short* __restrict__ h2t_h, unsigned short* __restrict__ h2t_l)
{
    __shared__ __align__(16) unsigned short Ahs[2][64 * LP];
    __shared__ __align__(16) unsigned short Als[2][64 * LP];
    __shared__ __align__(16) unsigned short Bhs[2][64 * LP];
    __shared__ __align__(16) unsigned short Bls[2][64 * LP];

    const int bx = blockIdx.x;
    const bool isH2 = (bx >= 64);
    const float* Afp; const unsigned short *Bh, *Bl;
    float* C;
    int Kfull, kbase, nIter, row0;
    if (!isH2) {
        Afp = video; Bh = w1t_h; Bl = w1t_l;
        Kfull = VDIM; kbase = (bx >> 5) * 512; nIter = 16;
        row0 = (bx & 31) * 64;
        C = h1p + (size_t)(bx >> 5) * MBP * ADIM;
    } else {
        Afp = text; Bh = w2t_h; Bl = w2t_l;
        Kfull = TDIM; kbase = 0; nIter = 24;
        row0 = (bx - 64) * 64;
        C = h2;
    }

    const int t = threadIdx.x;
    const int r  = t >> 2;
    const int kc = (t & 3) << 3;
    const int col0 = blockIdx.y * 64;
    const int wave = t >> 6, lane = t & 63;
    const int m15 = lane & 15, q8 = (lane >> 4) << 3;

    const size_t aoff = (size_t)(row0 + r) * Kfull + kbase + kc;
    const size_t boff = (size_t)(col0 + r) * Kfull + kbase + kc;

    floatx4 acc[4] = { {0.f,0.f,0.f,0.f}, {0.f,0.f,0.f,0.f},
                       {0.f,0.f,0.f,0.f}, {0.f,0.f,0.f,0.f} };

    float4 a0 = *(const float4*)(Afp + aoff);
    float4 a1 = *(const float4*)(Afp + aoff + 4);
    uint4 bvh = *(const uint4*)(Bh + boff);
    uint4 bvl = *(const uint4*)(Bl + boff);
    {
        uint4 avh, avl; split8(a0, a1, avh, avl);
        *(uint4*)&Ahs[0][r * LP + kc] = avh;
        *(uint4*)&Als[0][r * LP + kc] = avl;
        *(uint4*)&Bhs[0][r * LP + kc] = bvh;
        *(uint4*)&Bls[0][r * LP + kc] = bvl;
    }

    for (int i = 0; i < nIter; ++i) {
        __syncthreads();
        if (i + 1 < nIter) {
            int k0 = (i + 1) << 5;
            a0 = *(const float4*)(Afp + aoff + k0);
            a1 = *(const float4*)(Afp + aoff + k0 + 4);
            bvh = *(const uint4*)(Bh + boff + k0);
            bvl = *(const uint4*)(Bl + boff + k0);
        }
        const int cur = i & 1;
        short8 afh = *(const short8*)&Ahs[cur][(wave * 16 + m15) * LP + q8];
        short8 afl = *(const short8*)&Als[cur][(wave * 16 + m15) * LP + q8];
        #pragma unroll
        for (int j = 0; j < 4; ++j) {
            short8 bfh = *(const short8*)&Bhs[cur][(j * 16 + m15) * LP + q8];
            short8 bfl = *(const short8*)&Bls[cur][(j * 16 + m15) * LP + q8];
            acc[j] = __builtin_amdgcn_mfma_f32_16x16x32_bf16(afh, bfh, acc[j], 0, 0, 0);
            acc[j] = __builtin_amdgcn_mfma_f32_16x16x32_bf16(afh, bfl, acc[j], 0, 0, 0);
            acc[j] = __builtin_amdgcn_mfma_f32_16x16x32_bf16(afl, bfh, acc[j], 0, 0, 0);
        }
        if (i + 1 < nIter) {
            const int nxt = cur ^ 1;
            uint4 avh, avl; split8(a0, a1, avh, avl);
            *(uint4*)&Ahs[nxt][r * LP + kc] = avh;
            *(uint4*)&Als[nxt][r * LP + kc] = avl;
            *(uint4*)&Bhs[nxt][r * LP + kc] = bvh;
            *(uint4*)&Bls[nxt][r * LP + kc] = bvl;
        }
    }

    // C/D layout: col = lane&15, row = (lane>>4)*4 + reg
    const int rbase = row0 + wave * 16 + (q8 >> 1);
    #pragma unroll
    for (int j = 0; j < 4; ++j) {
        int col = col0 + j * 16 + m15;
        #pragma unroll
        for (int rr = 0; rr < 4; ++rr) {
            int row = rbase + rr;
            float v = acc[j][rr];
            C[(size_t)row * ADIM + col] = v;
            if (isH2) {
                // h2t[b][a][q]: b=row>>6, q=row&63, a=col
                size_t idx = (size_t)(row >> 6) * (ADIM * 64) + (size_t)col * 64 + (row & 63);
                unsigned short h = bf16r(v);
                h2t_h[idx] = h;
                h2t_l[idx] = bf16r(v - bf2f(h));
            }
        }
    }
}

// Additive-attention logits + softmax, lane<->a layout. acc[64] kept in VGPRs:
// ALL indexing static (round 8's runtime-hf index demoted acc to scratch ->
// 163 MB spill traffic, 45-59 us; both reduce halves now written explicitly).
__global__ __launch_bounds__(256, 2) void attn_scores(
    const float* __restrict__ h1p,   // [2][2048][512] K-split partials
    const float* __restrict__ h2,    // [8][64][512]
    const float* __restrict__ bias,  // [512]
    const float* __restrict__ w3,    // [512]
    float* __restrict__ sc)          // [2048][64] fp32 softmaxed
{
    __shared__ float h2s[64][132];   // 33.8 KB; also reused as reduce scratch

    const int bp0 = blockIdx.x * 4;
    const int b   = bp0 >> 8;
    const int t   = threadIdx.x, wave = t >> 6, lane = t & 63;
    const int p   = bp0 + wave;
    const float* h2b  = h2 + (size_t)b * 64 * ADIM;
    const float* h1a  = h1p + (size_t)p * ADIM;
    const float* h1b2 = h1p + (size_t)MBP * ADIM + (size_t)p * ADIM;

    float acc[64];
    #pragma unroll
    for (int q = 0; q < 64; ++q) acc[q] = 0.f;

    const int qrow = t >> 2, cch = t & 3;
    #pragma unroll 1
    for (int tile = 0; tile < 4; ++tile) {
        const int a0 = tile * 128;
        __syncthreads();   // prior tile's readers done
        #pragma unroll
        for (int j = 0; j < 8; ++j) {
            float4 v = *(const float4*)(h2b + (size_t)qrow * ADIM + a0 + (cch + 4 * j) * 4);
            *(float4*)&h2s[qrow][(cch + 4 * j) * 4] = v;
        }
        __syncthreads();
        const int ag0 = a0 + lane, ag1 = ag0 + 64;
        const float c0  = h1a[ag0] + h1b2[ag0] + bias[ag0];
        const float c1  = h1a[ag1] + h1b2[ag1] + bias[ag1];
        const float w30 = w3[ag0], w31 = w3[ag1];
        const float* hp = &h2s[0][lane];
        #pragma unroll
        for (int q = 0; q < 64; ++q) {
            acc[q] = __builtin_fmaf(tanh_fast(c0 + hp[q * 132]),      w30, acc[q]);
            acc[q] = __builtin_fmaf(tanh_fast(c1 + hp[q * 132 + 64]), w31, acc[q]);
        }
    }
    __syncthreads();       // all waves done with h2s before scratch reuse

    float* scr = &h2s[0][0] + wave * 2112;   // 64x33 fp32 per wave
    const int qq = lane & 31, r0 = (lane >> 5) * 32;
    float e = 0.f;

    // half 0: q = 0..31 (static acc indices)
    #pragma unroll
    for (int q = 0; q < 32; ++q) scr[lane * 33 + q] = acc[q];
    {
        float part = 0.f;
        #pragma unroll
        for (int j = 0; j < 32; ++j) part += scr[(r0 + j) * 33 + qq];
        part += __shfl_xor(part, 32, 64);
        if (lane < 32) e = part;
    }
    // half 1: q = 32..63 (static acc indices)
    #pragma unroll
    for (int q = 0; q < 32; ++q) scr[lane * 33 + q] = acc[32 + q];
    {
        float part = 0.f;
        #pragma unroll
        for (int j = 0; j < 32; ++j) part += scr[(r0 + j) * 33 + qq];
        part += __shfl_xor(part, 32, 64);
        if (lane >= 32) e = part;
    }

    // softmax across the wave (lane = q)
    float m = e;
    #pragma unroll
    for (int off = 32; off; off >>= 1) m = fmaxf(m, __shfl_xor(m, off, 64));
    float ex = __builtin_amdgcn_exp2f((e - m) * 1.44269504088896f);
    float s = ex;
    #pragma unroll
    for (int off = 32; off; off >>= 1) s += __shfl_xor(s, off, 64);
    sc[(size_t)p * 64 + lane] = ex * __builtin_amdgcn_rcpf(s);
}

// text_attn = scores @ h2 via compensated MFMA (scores rne-split in-register
// from fp32) + cont-feature epilogue -> tc bf16.
__global__ __launch_bounds__(256) void ta_cont(
    const float* __restrict__ sc32,            // [2048][64] fp32
    const unsigned short* __restrict__ h2t_h,  // [8][512][64]
    const unsigned short* __restrict__ h2t_l,  // [8][512][64]
    const float* __restrict__ h1p,             // [2][2048][512]
    unsigned short* __restrict__ tcont)        // [2048][2048] bf16
{
    const int row0 = blockIdx.x * 64;
    const int col0 = blockIdx.y * 64;
    const int b = row0 >> 8;
    const int t = threadIdx.x;
    const int wave = t >> 6, lane = t & 63;
    const int m15 = lane & 15, q8 = (lane >> 4) << 3;

    const float* ap = sc32 + (size_t)(row0 + wave * 16 + m15) * 64;
    short8 af0h, af0l, af1h, af1l;
    split8s(ap + q8, af0h, af0l);
    split8s(ap + q8 + 32, af1h, af1l);
    const size_t bbase = (size_t)b * ADIM * 64;

    floatx4 acc[4];
    #pragma unroll
    for (int j = 0; j < 4; ++j) {
        size_t boff = bbase + (size_t)(col0 + j * 16 + m15) * 64 + q8;
        short8 bf0h = *(const short8*)&h2t_h[boff];
        short8 bf1h = *(const short8*)&h2t_h[boff + 32];
        short8 bf0l = *(const short8*)&h2t_l[boff];
        short8 bf1l = *(const short8*)&h2t_l[boff + 32];
        floatx4 z = {0.f, 0.f, 0.f, 0.f};
        z = __builtin_amdgcn_mfma_f32_16x16x32_bf16(af0h, bf0h, z, 0, 0, 0);
        z = __builtin_amdgcn_mfma_f32_16x16x32_bf16(af0h, bf0l, z, 0, 0, 0);
        z = __builtin_amdgcn_mfma_f32_16x16x32_bf16(af0l, bf0h, z, 0, 0, 0);
        z = __builtin_amdgcn_mfma_f32_16x16x32_bf16(af1h, bf1h, z, 0, 0, 0);
        z = __builtin_amdgcn_mfma_f32_16x16x32_bf16(af1h, bf1l, z, 0, 0, 0);
        acc[j] = __builtin_amdgcn_mfma_f32_16x16x32_bf16(af1l, bf1h, z, 0, 0, 0);
    }

    const float* h1a  = h1p;
    const float* h1b2 = h1p + (size_t)MBP * ADIM;
    const int rbase = row0 + wave * 16 + (q8 >> 1);
    #pragma unroll
    for (int j = 0; j < 4; ++j) {
        int a = col0 + j * 16 + m15;
        #pragma unroll
        for (int rr = 0; rr < 4; ++rr) {
            int row = rbase + rr;
            float ta = acc[j][rr];
            size_t hi = (size_t)row * ADIM + a;
            float hh = h1a[hi] + h1b2[hi];
            unsigned short* o = tcont + (size_t)row * CDIM;
            o[a]            = bf16r(tanh_fast(hh));
            o[ADIM + a]     = bf16r(tanh_fast(ta));
            o[2 * ADIM + a] = bf16r(tanh_fast(hh * ta));
            o[3 * ADIM + a] = bf16r(tanh_fast(hh - ta));
        }
    }
}

// Final GEMM, K-split x4 via blockIdx.z -> fp32 partials (pitch 512, no bias).
__global__ __launch_bounds__(256) void gemm_bf16(
    const unsigned short* __restrict__ A, const unsigned short* __restrict__ Bt,
    float* __restrict__ P)
{
    __shared__ __align__(16) unsigned short As[2][64 * LP];
    __shared__ __align__(16) unsigned short Bs[2][64 * LP];

    const int t = threadIdx.x;
    const int r  = t >> 2;
    const int kc = (t & 3) << 3;
    const int row0 = blockIdx.x * 64, col0 = blockIdx.y * 64;
    const int kbase = blockIdx.z * 512;
    const int wave = t >> 6, lane = t & 63;
    const int m15 = lane & 15, q8 = (lane >> 4) << 3;

    const unsigned short* Ap = A + (size_t)(row0 + r) * CDIM + kbase + kc;
    const int bn = col0 + r;
    const unsigned short* Bp = Bt + (size_t)bn * CDIM + kbase + kc;
    const bool bvalid = (bn < NOUT);

    floatx4 acc[4] = { {0.f,0.f,0.f,0.f}, {0.f,0.f,0.f,0.f},
                       {0.f,0.f,0.f,0.f}, {0.f,0.f,0.f,0.f} };

    uint4 av = *(const uint4*)Ap;
    uint4 bv = {0u,0u,0u,0u};
    if (bvalid) bv = *(const uint4*)Bp;
    *(uint4*)&As[0][r * LP + kc] = av;
    *(uint4*)&Bs[0][r * LP + kc] = bv;

    const int nIter = 16;
    for (int i = 0; i < nIter; ++i) {
        __syncthreads();
        if (i + 1 < nIter) {
            int k0 = (i + 1) << 5;
            av = *(const uint4*)(Ap + k0);
            if (bvalid) bv = *(const uint4*)(Bp + k0);
        }
        const int cur = i & 1;
        short8 af = *(const short8*)&As[cur][(wave * 16 + m15) * LP + q8];
        #pragma unroll
        for (int j = 0; j < 4; ++j) {
            short8 bf = *(const short8*)&Bs[cur][(j * 16 + m15) * LP + q8];
            acc[j] = __builtin_amdgcn_mfma_f32_16x16x32_bf16(af, bf, acc[j], 0, 0, 0);
        }
        if (i + 1 < nIter) {
            const int nxt = cur ^ 1;
            *(uint4*)&As[nxt][r * LP + kc] = av;
            *(uint4*)&Bs[nxt][r * LP + kc] = bv;
        }
    }

    float* Pz = P + (size_t)blockIdx.z * MBP * 512;
    const int rbase = row0 + wave * 16 + (q8 >> 1);
    #pragma unroll
    for (int j = 0; j < 4; ++j) {
        int col = col0 + j * 16 + m15;
        if (col < NOUT) {
            #pragma unroll
            for (int rr = 0; rr < 4; ++rr)
                Pz[(size_t)(rbase + rr) * 512 + col] = acc[j][rr];
        }
    }
}

// out[row][col] = b4[col] + sum_z part[z][row][col]; float2 per thread.
__global__ __launch_bounds__(256) void reduce_bias(
    const float* __restrict__ P, const float* __restrict__ b4,
    float* __restrict__ out)
{
    int i = blockIdx.x * 256 + threadIdx.x;      // float2 index
    if (i >= MBP * (NOUT / 2)) return;
    int row = i / (NOUT / 2);
    int col = (i - row * (NOUT / 2)) * 2;
    const float* p = P + (size_t)row * 512 + col;
    float2 v = *(const float2*)(b4 + col);
    #pragma unroll
    for (int z = 0; z < 4; ++z) {
        float2 q = *(const float2*)(p + (size_t)z * MBP * 512);
        v.x += q.x; v.y += q.y;
    }
    *(float2*)(out + (size_t)row * NOUT + col) = v;
}

extern "C" void kernel_launch(void* const* d_in, const int* in_sizes, int n_in,
                              void* d_out, int out_size, void* d_ws, size_t ws_size,
                              hipStream_t stream) {
    const float* video = (const float*)d_in[0];  // [8,256,1024]
    const float* text  = (const float*)d_in[1];  // [8,64,768]
    // masks (d_in[2], d_in[3]) are dead in the reference
    const float* w1   = (const float*)d_in[4];   // [1024,512]
    const float* w2   = (const float*)d_in[5];   // [768,512]
    const float* w3   = (const float*)d_in[6];   // [512,1]
    const float* bias = (const float*)d_in[7];   // [512]
    const float* w4   = (const float*)d_in[8];   // [2048,500]
    const float* b4   = (const float*)d_in[9];   // [500]
    float* out = (float*)d_out;                  // [8,256,500]

    char* ws = (char*)d_ws;
    size_t off = 0;
    unsigned short* w1t_h = (unsigned short*)(ws + off); off += (size_t)ADIM * VDIM * 2;
    unsigned short* w1t_l = (unsigned short*)(ws + off); off += (size_t)ADIM * VDIM * 2;
    unsigned short* w2t_h = (unsigned short*)(ws + off); off += (size_t)ADIM * TDIM * 2;
    unsigned short* w2t_l = (unsigned short*)(ws + off); off += (size_t)ADIM * TDIM * 2;
    unsigned short* w4t   = (unsigned short*)(ws + off); off += (size_t)NOUT * CDIM * 2;
    float*          h1p   = (float*)(ws + off);          off += (size_t)2 * MBP * ADIM * 4;
    float*          h2    = (float*)(ws + off);          off += (size_t)MT * ADIM * 4;
    unsigned short* h2t_h = (unsigned short*)(ws + off); off += (size_t)8 * ADIM * 64 * 2;
    unsigned short* h2t_l = (unsigned short*)(ws + off); off += (size_t)8 * ADIM * 64 * 2;
    float*          sc32  = (float*)(ws + off);          off += (size_t)MBP * 64 * 4;
    unsigned short* tc    = (unsigned short*)(ws + off); off += (size_t)MBP * CDIM * 2;
    float*          gpart = (float*)(ws + off);          off += (size_t)4 * MBP * 512 * 4;

    // 1) weight transposes (w1/w2 split, w4 single)
    prep<<<1920, 256, 0, stream>>>(w1, w2, w4, w1t_h, w1t_l, w2t_h, w2t_l, w4t);

    // 2) h1 (K-split x2 partials) & h2 GEMMs, A converted inline; h2t epilogue
    gemm3_both<<<dim3(72, 8), 256, 0, stream>>>(video, text, w1t_h, w1t_l,
                                                w2t_h, w2t_l, h1p, h2, h2t_h, h2t_l);

    // 3) logits + softmax -> fp32 scores
    attn_scores<<<MBP / 4, 256, 0, stream>>>(h1p, h2, bias, w3, sc32);

    // 4) text_attn MFMA + cont features -> tc bf16
    ta_cont<<<dim3(MBP / 64, ADIM / 64), 256, 0, stream>>>(sc32, h2t_h, h2t_l, h1p, tc);

    // 5) out partials: tanh(cont) @ w4, K-split x4
    gemm_bf16<<<dim3(MBP / 64, 8, 4), 256, 0, stream>>>(tc, w4t, gpart);

    // 6) sum partials + bias
    reduce_bias<<<(MBP * (NOUT / 2) + 255) / 256, 256, 0, stream>>>(gpart, b4, out);
}